// Round 7
// baseline (241.249 us; speedup 1.0000x reference)
//
#include <hip/hip_runtime.h>
#include <hip/hip_bf16.h>
#include <hip/hip_fp16.h>

#define LEAK   0.2f
#define NPB    100      // nodes per dst-bucket -> K = ceil(N/NPB) = 1000
#define CAP    4096     // padded per-bucket capacity (mean 3200, sigma 57)
#define CAPSH  12       // log2(CAP)
#define SBITS  17       // bits for src id (N=100000 < 2^17)
#define SMASK  0x1FFFF
#define CHUNKB 8192     // edges per kbin block (16 per thread at 512 thr)

__device__ __forceinline__ unsigned pkh(float a, float b) {
    __half2 h = __floats2half2_rn(a, b);
    return *(unsigned*)&h;
}
__device__ __forceinline__ float2 uph(unsigned u) {
    __half2 h = *(__half2*)&u;
    return __half22float2(h);
}

// ---------------------------------------------------------------------------
// kbin: layout probe, LDS bucket histogram (1024 buckets now), one global
// atomic per (block,bucket), scattered packed writes. Plain loads/stores
// (NT falsified R4/R5). K=1000 buckets -> hist arrays 1024, two strided
// passes for zero/reserve.
// ---------------------------------------------------------------------------
__global__ __launch_bounds__(512) void kbin(const int* __restrict__ ei, int E, int K,
                                            int* __restrict__ cursor,
                                            int* __restrict__ binned) {
    __shared__ int hist[1024], gb[1024], lc[1024];
    __shared__ int probe;
    int t = threadIdx.x;
    hist[t] = 0;
    hist[t + 512] = 0;
    if (t == 0) probe = 0;
    __syncthreads();
    // int64 LE => odd int32 slots of first 1024 values are 0
    if (t < 256) {
        int zc = 0;
#pragma unroll
        for (int j = 0; j < 4; j++) zc += (ei[(t * 4 + j) * 2 + 1] == 0) ? 1 : 0;
        if (zc) atomicAdd(&probe, zc);
    }
    __syncthreads();
    int f = (probe == 1024);
    int e0 = blockIdx.x * CHUNKB;
    int ss[16], dd[16];
#pragma unroll
    for (int i = 0; i < 16; i++) {
        int e = e0 + t + 512 * i;
        ss[i] = -1;
        dd[i] = 0;
        if (e < E) {
            int s, d;
            if (f) { s = ei[2 * e]; d = ei[2 * (e + E)]; }
            else   { s = ei[e];     d = ei[e + E]; }
            ss[i] = s;
            dd[i] = d;
            atomicAdd(&hist[d / NPB], 1);
        }
    }
    __syncthreads();
    for (int u = t; u < 1024; u += 512) {
        int h = hist[u];
        lc[u] = 0;
        if (u < K && h) gb[u] = (u << CAPSH) + atomicAdd(&cursor[u], h);
    }
    __syncthreads();
#pragma unroll
    for (int i = 0; i < 16; i++) {
        if (ss[i] >= 0) {
            int bk = dd[i] / NPB;
            int dloc = dd[i] - bk * NPB;
            int pos = atomicAdd(&lc[bk], 1);
            int gpos = gb[bk] + pos;
            if (gpos < ((bk + 1) << CAPSH))           // OOB safety clamp
                binned[gpos] = ss[i] | (dloc << SBITS);
        }
    }
}

// ---------------------------------------------------------------------------
// k1: h1[N,32](fp16) = x[N,128] @ W1[128,32]; a1s/a1d[N,2] attention scalars.
// Block 0 additionally zeroes the kbin cursor (replaces the hipMemsetAsync
// dispatch; k1 is launched BEFORE kbin so stream order makes this safe).
// ---------------------------------------------------------------------------
__global__ __launch_bounds__(256) void k1(const float* __restrict__ x,
                                          const float* __restrict__ W1,
                                          const float* __restrict__ atts,
                                          const float* __restrict__ attd,
                                          uint2* __restrict__ h1h,
                                          float* __restrict__ a1s,
                                          float* __restrict__ a1d, int N,
                                          int* __restrict__ cursor, int K) {
    __shared__ float Ws[128 * 32];
    __shared__ float xs[64 * 132];
    int t = threadIdx.x;
    if (blockIdx.x == 0) {
        for (int u = t; u < K; u += 256) cursor[u] = 0;
    }
    const float4* W4 = (const float4*)W1;
    float4* Ws4 = (float4*)Ws;
#pragma unroll
    for (int i = 0; i < 4; i++) Ws4[t + 256 * i] = W4[t + 256 * i];
    long long node0 = (long long)blockIdx.x * 64;
    const float4* x4 = (const float4*)x;
    float4* xs4 = (float4*)xs;
#pragma unroll
    for (int i = 0; i < 8; i++) {
        int idx = t + 256 * i;
        int row = idx >> 5, col = idx & 31;
        long long n = node0 + row;
        float4 v = make_float4(0.f, 0.f, 0.f, 0.f);
        if (n < N) v = x4[n * 32 + col];
        xs4[row * 33 + col] = v;
    }
    __syncthreads();

    int cg = t & 7, ns = t >> 3;
    const float4* xr0 = (const float4*)(xs + (ns * 2) * 132);
    const float4* xr1 = (const float4*)(xs + (ns * 2 + 1) * 132);
    float acc0[4] = {0.f, 0.f, 0.f, 0.f}, acc1[4] = {0.f, 0.f, 0.f, 0.f};
#pragma unroll 8
    for (int k4 = 0; k4 < 32; k4++) {
        float4 xa = xr0[k4], xb = xr1[k4];
        float av[4] = {xa.x, xa.y, xa.z, xa.w};
        float bv[4] = {xb.x, xb.y, xb.z, xb.w};
#pragma unroll
        for (int i = 0; i < 4; i++) {
            float4 w = Ws4[(k4 * 4 + i) * 8 + cg];
            acc0[0] = fmaf(av[i], w.x, acc0[0]);
            acc0[1] = fmaf(av[i], w.y, acc0[1]);
            acc0[2] = fmaf(av[i], w.z, acc0[2]);
            acc0[3] = fmaf(av[i], w.w, acc0[3]);
            acc1[0] = fmaf(bv[i], w.x, acc1[0]);
            acc1[1] = fmaf(bv[i], w.y, acc1[1]);
            acc1[2] = fmaf(bv[i], w.z, acc1[2]);
            acc1[3] = fmaf(bv[i], w.w, acc1[3]);
        }
    }
    long long gn0 = node0 + ns * 2, gn1 = gn0 + 1;
    if (gn0 < N) h1h[gn0 * 8 + cg] = make_uint2(pkh(acc0[0], acc0[1]),
                                                pkh(acc0[2], acc0[3]));
    if (gn1 < N) h1h[gn1 * 8 + cg] = make_uint2(pkh(acc1[0], acc1[1]),
                                                pkh(acc1[2], acc1[3]));

    float ps0 = 0.f, pd0 = 0.f, ps1 = 0.f, pd1 = 0.f;
#pragma unroll
    for (int i = 0; i < 4; i++) {
        float aa = atts[cg * 4 + i], dd = attd[cg * 4 + i];
        ps0 = fmaf(acc0[i], aa, ps0);
        pd0 = fmaf(acc0[i], dd, pd0);
        ps1 = fmaf(acc1[i], aa, ps1);
        pd1 = fmaf(acc1[i], dd, pd1);
    }
#pragma unroll
    for (int m = 1; m < 4; m <<= 1) {
        ps0 += __shfl_xor(ps0, m, 64);
        pd0 += __shfl_xor(pd0, m, 64);
        ps1 += __shfl_xor(ps1, m, 64);
        pd1 += __shfl_xor(pd1, m, 64);
    }
    if ((cg & 3) == 0) {
        int hd = cg >> 2;
        if (gn0 < N) { a1s[gn0 * 2 + hd] = ps0; a1d[gn0 * 2 + hd] = pd0; }
        if (gn1 < N) { a1s[gn1 * 2 + hd] = ps1; a1d[gn1 * 2 + hd] = pd1; }
    }
}

// ---------------------------------------------------------------------------
// kfused: one block per bucket. NOW 512 threads / NPB=100 / CAP=4096:
// ~17.6 KB LDS -> 4 blocks/CU (vs 2 at 1024 thr), 1000 blocks (~3.9/CU)
// -> higher occupancy + 4 independent barrier domains per CU to hide the
// latency-bound h1h gather (R6: occupancy 61%, 2.2 TB/s on 114 MB FETCH).
// Phase 2 keeps the proven 8x8 layout with unroll x2.
// ---------------------------------------------------------------------------
__global__ __launch_bounds__(512, 8) void kfused(const int* __restrict__ cursor,
                                                 const int* __restrict__ binned,
                                                 const uint2* __restrict__ h1h,
                                                 const float* __restrict__ a1s,
                                                 const float* __restrict__ a1d,
                                                 const float* __restrict__ b1,
                                                 const float* __restrict__ W2,
                                                 const float* __restrict__ as2,
                                                 const float* __restrict__ ad2,
                                                 float4* __restrict__ pk,
                                                 int* __restrict__ srcs,
                                                 int* __restrict__ od, int N) {
    __shared__ int lsrc[CAP];                 // 16 KB
    __shared__ int ldeg[NPB], lcur[NPB], loff[NPB];
    __shared__ int swt[2];
    int b = blockIdx.x, t = threadIdx.x;
    int node0 = b * NPB;
    int nn = min(NPB, N - node0);
    int cnt = cursor[b];
    if (cnt > CAP) cnt = CAP;
    const int* bb = binned + ((long long)b << CAPSH);
    if (t < NPB) ldeg[t] = 0;
    __syncthreads();
    int pv[8];
#pragma unroll
    for (int j = 0; j < 8; j++) {
        int i = t + 512 * j;
        pv[j] = (i < cnt) ? bb[i] : -1;
        if (pv[j] >= 0) atomicAdd(&ldeg[pv[j] >> SBITS], 1);
    }
    __syncthreads();
    // exclusive scan over nn (<=100) nodes: first 2 waves + shuffles
    {
        int v = 0, xsc = 0;
        if (t < 128) {
            v = (t < nn) ? ldeg[t] : 0;
            xsc = v;
#pragma unroll
            for (int o = 1; o < 64; o <<= 1) {
                int y = __shfl_up(xsc, o, 64);
                if ((t & 63) >= o) xsc += y;
            }
            if ((t & 63) == 63) swt[t >> 6] = xsc;
        }
        __syncthreads();
        if (t < 128) {
            if (t >= 64) xsc += swt[0];
            if (t < nn) {
                int rel = xsc - v;
                loff[t] = rel;
                lcur[t] = rel;
                od[node0 + t] = rel | (v << 14);   // rel < 4096 fits 14 bits
            }
        }
        __syncthreads();
    }
#pragma unroll
    for (int j = 0; j < 8; j++) {
        if (pv[j] >= 0) {
            int pos = atomicAdd(&lcur[pv[j] >> SBITS], 1);
            lsrc[pos] = pv[j] & SMASK;
        }
    }
    __syncthreads();
    // srcs for kagg2 (coalesced stream write)
    for (int i = t; i < cnt; i += 512) srcs[((long long)b << CAPSH) + i] = lsrc[i];

    // ---- phase 2 (8 edges x 8 ch-quads, unroll x2), 8 waves ----
    int wv = t >> 6, lane = t & 63;
    int e8 = lane >> 3, c4 = lane & 7, hd = c4 >> 2;
    bool wlane = (c4 & 3) == 0;
    for (int ni = wv; ni < nn; ni += 8) {
        int n = node0 + ni;
        float a1dn = a1d[2 * n + hd];
        int base = loff[ni], g = ldeg[ni];
        float4 acc = make_float4(0.f, 0.f, 0.f, 0.f);
        float wsum = 0.f;
        // tt = -1 is the self-loop (edge slot 0); pair (tt, tt+8) per iter
        for (int tt = e8 - 1; tt < g; tt += 16) {
            int t2 = tt + 8;
            bool p2 = t2 < g;
            int s0 = (tt < 0) ? n : lsrc[base + tt];
            int s1 = p2 ? lsrc[base + t2] : s0;       // safe addr when !p2
            // issue all four global loads back-to-back (MLP)
            float as0 = a1s[2 * s0 + hd];
            float as1 = a1s[2 * s1 + hd];
            uint2 hb0 = h1h[(size_t)s0 * 8 + c4];
            uint2 hb1 = h1h[(size_t)s1 * 8 + c4];
            float al0 = as0 + a1dn;
            al0 = al0 > 0.f ? al0 : LEAK * al0;
            float w0 = __expf(al0);
            float al1 = as1 + a1dn;
            al1 = al1 > 0.f ? al1 : LEAK * al1;
            float w1 = p2 ? __expf(al1) : 0.f;
            float2 f01 = uph(hb0.x), f23 = uph(hb0.y);
            float2 g01 = uph(hb1.x), g23 = uph(hb1.y);
            acc.x = fmaf(w0, f01.x, acc.x);
            acc.y = fmaf(w0, f01.y, acc.y);
            acc.z = fmaf(w0, f23.x, acc.z);
            acc.w = fmaf(w0, f23.y, acc.w);
            acc.x = fmaf(w1, g01.x, acc.x);
            acc.y = fmaf(w1, g01.y, acc.y);
            acc.z = fmaf(w1, g23.x, acc.z);
            acc.w = fmaf(w1, g23.y, acc.w);
            if (wlane) wsum += w0 + w1;
        }
#pragma unroll
        for (int m = 8; m < 64; m <<= 1) {
            acc.x += __shfl_xor(acc.x, m, 64);
            acc.y += __shfl_xor(acc.y, m, 64);
            acc.z += __shfl_xor(acc.z, m, 64);
            acc.w += __shfl_xor(acc.w, m, 64);
            wsum += __shfl_xor(wsum, m, 64);
        }
        float wsH = __shfl(wsum, hd * 4, 64);
        float inv = 1.f / (wsH + 1e-16f);
        float4 bv = ((const float4*)b1)[c4];
        float4 t1;
        t1.x = acc.x * inv + bv.x;
        t1.y = acc.y * inv + bv.y;
        t1.z = acc.z * inv + bv.z;
        t1.w = acc.w * inv + bv.w;
        t1.x = t1.x > 0.f ? t1.x : __expf(t1.x) - 1.f;
        t1.y = t1.y > 0.f ? t1.y : __expf(t1.y) - 1.f;
        t1.z = t1.z > 0.f ? t1.z : __expf(t1.z) - 1.f;
        t1.w = t1.w > 0.f ? t1.w : __expf(t1.w) - 1.f;
        const float4* W24 = (const float4*)W2;
        float4 wA = W24[c4 * 2], wB = W24[c4 * 2 + 1];
        float p0 = t1.x * wA.x + t1.y * wA.z + t1.z * wB.x + t1.w * wB.z;
        float p1 = t1.x * wA.y + t1.y * wA.w + t1.z * wB.y + t1.w * wB.w;
#pragma unroll
        for (int m = 1; m < 8; m <<= 1) {
            p0 += __shfl_xor(p0, m, 64);
            p1 += __shfl_xor(p1, m, 64);
        }
        if (lane == 0)
            pk[n] = make_float4(p0 * as2[0] + p1 * as2[1], p0, p1,
                                p0 * ad2[0] + p1 * ad2[1]);
    }
}

// ---------------------------------------------------------------------------
// kagg2: layer-2 gather, 32-lane subgroup per node, 1 packed 16B pk load per
// edge, log_softmax -> out. NPB/CAPSH updated.
// ---------------------------------------------------------------------------
__global__ __launch_bounds__(256) void kagg2(const int* __restrict__ od,
                                             const int* __restrict__ srcs,
                                             const float4* __restrict__ pk,
                                             const float* __restrict__ b2,
                                             float* __restrict__ out, int N) {
    int sub = threadIdx.x >> 5, k = threadIdx.x & 31;
    int n = blockIdx.x * 8 + sub;
    if (n >= N) return;
    float4 pn = pk[n];
    float adn = pn.w;
    int o = od[n];
    int base = ((n / NPB) << CAPSH) + (o & 16383);
    int g = o >> 14;
    float a0 = 0.f, a1v = 0.f, wsm = 0.f;
    // e = -1 is the self-loop
    for (int e = k - 1; e < g; e += 32) {
        float4 p = (e < 0) ? pn : pk[srcs[base + e]];
        float al = p.x + adn;
        al = al > 0.f ? al : LEAK * al;
        float w = __expf(al);
        a0 = fmaf(w, p.y, a0);
        a1v = fmaf(w, p.z, a1v);
        wsm += w;
    }
#pragma unroll
    for (int m = 1; m < 32; m <<= 1) {
        a0 += __shfl_xor(a0, m, 32);
        a1v += __shfl_xor(a1v, m, 32);
        wsm += __shfl_xor(wsm, m, 32);
    }
    if (k == 0) {
        float inv = 1.f / (wsm + 1e-16f);
        float o0 = a0 * inv + b2[0];
        float o1 = a1v * inv + b2[1];
        float mx = fmaxf(o0, o1);
        float lse = mx + __logf(__expf(o0 - mx) + __expf(o1 - mx));
        ((float2*)out)[n] = make_float2(o0 - lse, o1 - lse);
    }
}

extern "C" void kernel_launch(void* const* d_in, const int* in_sizes, int n_in,
                              void* d_out, int out_size, void* d_ws, size_t ws_size,
                              hipStream_t stream) {
    const float* x   = (const float*)d_in[0];
    const int*   ei  = (const int*)d_in[1];
    const float* W1  = (const float*)d_in[2];
    const float* as1 = (const float*)d_in[3];
    const float* ad1 = (const float*)d_in[4];
    const float* b1  = (const float*)d_in[5];
    const float* W2  = (const float*)d_in[6];
    const float* as2 = (const float*)d_in[7];
    const float* ad2 = (const float*)d_in[8];
    const float* b2  = (const float*)d_in[9];
    float* out = (float*)d_out;

    int N = out_size / 2;          // 100000
    int E = in_sizes[1] / 2;       // 3200000
    int K = (N + NPB - 1) / NPB;   // 1000

    // workspace layout (4B units; pk first for 16B alignment)
    float* wsp   = (float*)d_ws;
    float4* pk   = (float4*)wsp;                     // N float4
    uint2* h1h   = (uint2*)(pk + (size_t)N);         // N*8 uint2 (fp16 h1)
    float* a1s   = (float*)(h1h + (size_t)N * 8);    // N*2
    float* a1d   = a1s + (size_t)N * 2;              // N*2
    int* od      = (int*)(a1d + (size_t)N * 2);      // N
    int* srcs    = od + N;                           // K*CAP
    int* binned  = srcs + (size_t)K * CAP;           // K*CAP
    int* cursor  = binned + (size_t)K * CAP;         // K

    int nblkB = (E + CHUNKB - 1) / CHUNKB;           // 391

    // k1 first: its block 0 zeroes cursor (replaces hipMemsetAsync dispatch)
    k1<<<(N + 63) / 64, 256, 0, stream>>>(x, W1, as1, ad1, h1h, a1s, a1d, N,
                                          cursor, K);
    kbin<<<nblkB, 512, 0, stream>>>(ei, E, K, cursor, binned);
    kfused<<<K, 512, 0, stream>>>(cursor, binned, h1h, a1s, a1d,
                                  b1, W2, as2, ad2, pk, srcs, od, N);
    kagg2<<<(N + 7) / 8, 256, 0, stream>>>(od, srcs, pk, b2, out, N);
}

// Round 8
// 230.904 us; speedup vs baseline: 1.0448x; 1.0448x over previous
//
#include <hip/hip_runtime.h>
#include <hip/hip_bf16.h>
#include <hip/hip_fp16.h>

#define LEAK   0.2f
#define NPB    200      // nodes per dst-bucket -> K = ceil(N/NPB) = 500
#define CAP    8192     // padded per-bucket capacity (mean 6400, sigma 80)
#define CAPSH  13       // log2(CAP)
#define SBITS  17       // bits for src id (N=100000 < 2^17)
#define SMASK  0x1FFFF
#define CHUNKB 8192     // edges per kbin block (16 per thread at 512 thr)

__device__ __forceinline__ unsigned pkh(float a, float b) {
    __half2 h = __floats2half2_rn(a, b);
    return *(unsigned*)&h;
}
__device__ __forceinline__ float2 uph(unsigned u) {
    __half2 h = *(__half2*)&u;
    return __half22float2(h);
}

// ---------------------------------------------------------------------------
// kbin (write-coalesced): layout probe, LDS bucket histogram, global atomic
// reservation per (block,bucket) -- all as proven.  NEW: edges are counting-
// sorted into LDS (wave-scan of hist -> LDS scatter), then written to binned
// by a slot-parallel coalesced copy: consecutive lanes hit consecutive
// addresses inside each bucket run (~5 line groups per wave vs 64 scattered).
// rbk[slot] (uint16) maps LDS slot -> bucket for address computation.
// LDS ~56 KB -> 2 blocks/CU (grid is 391 blocks, 1.5/CU -- grid-limited).
// ---------------------------------------------------------------------------
__global__ __launch_bounds__(512) void kbin(const int* __restrict__ ei, int E, int K,
                                            int* __restrict__ cursor,
                                            int* __restrict__ binned) {
    __shared__ int hist[512], gb[512], lbase[512], lcur[512];
    __shared__ unsigned short rbk[CHUNKB];   // 16 KB: LDS slot -> bucket
    __shared__ int sv[CHUNKB];               // 32 KB: sorted packed edges
    __shared__ int swt[8];
    __shared__ int probe;
    int t = threadIdx.x;
    hist[t] = 0;
    if (t == 0) probe = 0;
    __syncthreads();
    // int64 LE => odd int32 slots of first 1024 values are 0
    if (t < 256) {
        int zc = 0;
#pragma unroll
        for (int j = 0; j < 4; j++) zc += (ei[(t * 4 + j) * 2 + 1] == 0) ? 1 : 0;
        if (zc) atomicAdd(&probe, zc);
    }
    __syncthreads();
    int f = (probe == 1024);
    int e0 = blockIdx.x * CHUNKB;
    int ss[16], dd[16];
#pragma unroll
    for (int i = 0; i < 16; i++) {
        int e = e0 + t + 512 * i;
        ss[i] = -1;
        dd[i] = 0;
        if (e < E) {
            int s, d;
            if (f) { s = ei[2 * e]; d = ei[2 * (e + E)]; }
            else   { s = ei[e];     d = ei[e + E]; }
            ss[i] = s;
            dd[i] = d;
            atomicAdd(&hist[d / NPB], 1);
        }
    }
    __syncthreads();
    // global reservation + LDS exclusive scan over 512 bucket slots
    int h = (t < K) ? hist[t] : 0;
    if (h) gb[t] = (t << CAPSH) + atomicAdd(&cursor[t], h);
    int xsc = h;
#pragma unroll
    for (int o = 1; o < 64; o <<= 1) {
        int y = __shfl_up(xsc, o, 64);
        if ((t & 63) >= o) xsc += y;
    }
    if ((t & 63) == 63) swt[t >> 6] = xsc;
    __syncthreads();
    int add = 0;
#pragma unroll
    for (int j = 0; j < 8; j++)
        if (j < (t >> 6)) add += swt[j];
    int lb = xsc - h + add;          // exclusive prefix = LDS run base
    lbase[t] = lb;
    lcur[t] = lb;
    __syncthreads();
    // fill slot->bucket map + scatter edges into LDS (disjoint arrays)
    for (int j = 0; j < h; j++) rbk[lb + j] = (unsigned short)t;
#pragma unroll
    for (int i = 0; i < 16; i++) {
        if (ss[i] >= 0) {
            int bk = dd[i] / NPB;
            int dloc = dd[i] - bk * NPB;
            int pos = atomicAdd(&lcur[bk], 1);
            sv[pos] = ss[i] | (dloc << SBITS);
        }
    }
    __syncthreads();
    // coalesced copy-out: consecutive slots -> consecutive global addresses
    int tot = min(CHUNKB, E - e0);
    for (int i = t; i < tot; i += 512) {
        int bk = rbk[i];
        int gpos = gb[bk] + (i - lbase[bk]);
        if (gpos < ((bk + 1) << CAPSH))           // OOB safety clamp
            binned[gpos] = sv[i];
    }
}

// ---------------------------------------------------------------------------
// k1: h1[N,32](fp16) = x[N,128] @ W1[128,32]; a1s/a1d[N,2] attention scalars.
// Block 0 additionally zeroes the kbin cursor (replaces the hipMemsetAsync
// dispatch; k1 is launched BEFORE kbin so stream order makes this safe).
// ---------------------------------------------------------------------------
__global__ __launch_bounds__(256) void k1(const float* __restrict__ x,
                                          const float* __restrict__ W1,
                                          const float* __restrict__ atts,
                                          const float* __restrict__ attd,
                                          uint2* __restrict__ h1h,
                                          float* __restrict__ a1s,
                                          float* __restrict__ a1d, int N,
                                          int* __restrict__ cursor, int K) {
    __shared__ float Ws[128 * 32];
    __shared__ float xs[64 * 132];
    int t = threadIdx.x;
    if (blockIdx.x == 0) {
        for (int u = t; u < K; u += 256) cursor[u] = 0;
    }
    const float4* W4 = (const float4*)W1;
    float4* Ws4 = (float4*)Ws;
#pragma unroll
    for (int i = 0; i < 4; i++) Ws4[t + 256 * i] = W4[t + 256 * i];
    long long node0 = (long long)blockIdx.x * 64;
    const float4* x4 = (const float4*)x;
    float4* xs4 = (float4*)xs;
#pragma unroll
    for (int i = 0; i < 8; i++) {
        int idx = t + 256 * i;
        int row = idx >> 5, col = idx & 31;
        long long n = node0 + row;
        float4 v = make_float4(0.f, 0.f, 0.f, 0.f);
        if (n < N) v = x4[n * 32 + col];
        xs4[row * 33 + col] = v;
    }
    __syncthreads();

    int cg = t & 7, ns = t >> 3;
    const float4* xr0 = (const float4*)(xs + (ns * 2) * 132);
    const float4* xr1 = (const float4*)(xs + (ns * 2 + 1) * 132);
    float acc0[4] = {0.f, 0.f, 0.f, 0.f}, acc1[4] = {0.f, 0.f, 0.f, 0.f};
#pragma unroll 8
    for (int k4 = 0; k4 < 32; k4++) {
        float4 xa = xr0[k4], xb = xr1[k4];
        float av[4] = {xa.x, xa.y, xa.z, xa.w};
        float bv[4] = {xb.x, xb.y, xb.z, xb.w};
#pragma unroll
        for (int i = 0; i < 4; i++) {
            float4 w = Ws4[(k4 * 4 + i) * 8 + cg];
            acc0[0] = fmaf(av[i], w.x, acc0[0]);
            acc0[1] = fmaf(av[i], w.y, acc0[1]);
            acc0[2] = fmaf(av[i], w.z, acc0[2]);
            acc0[3] = fmaf(av[i], w.w, acc0[3]);
            acc1[0] = fmaf(bv[i], w.x, acc1[0]);
            acc1[1] = fmaf(bv[i], w.y, acc1[1]);
            acc1[2] = fmaf(bv[i], w.z, acc1[2]);
            acc1[3] = fmaf(bv[i], w.w, acc1[3]);
        }
    }
    long long gn0 = node0 + ns * 2, gn1 = gn0 + 1;
    if (gn0 < N) h1h[gn0 * 8 + cg] = make_uint2(pkh(acc0[0], acc0[1]),
                                                pkh(acc0[2], acc0[3]));
    if (gn1 < N) h1h[gn1 * 8 + cg] = make_uint2(pkh(acc1[0], acc1[1]),
                                                pkh(acc1[2], acc1[3]));

    float ps0 = 0.f, pd0 = 0.f, ps1 = 0.f, pd1 = 0.f;
#pragma unroll
    for (int i = 0; i < 4; i++) {
        float aa = atts[cg * 4 + i], dd = attd[cg * 4 + i];
        ps0 = fmaf(acc0[i], aa, ps0);
        pd0 = fmaf(acc0[i], dd, pd0);
        ps1 = fmaf(acc1[i], aa, ps1);
        pd1 = fmaf(acc1[i], dd, pd1);
    }
#pragma unroll
    for (int m = 1; m < 4; m <<= 1) {
        ps0 += __shfl_xor(ps0, m, 64);
        pd0 += __shfl_xor(pd0, m, 64);
        ps1 += __shfl_xor(ps1, m, 64);
        pd1 += __shfl_xor(pd1, m, 64);
    }
    if ((cg & 3) == 0) {
        int hd = cg >> 2;
        if (gn0 < N) { a1s[gn0 * 2 + hd] = ps0; a1d[gn0 * 2 + hd] = pd0; }
        if (gn1 < N) { a1s[gn1 * 2 + hd] = ps1; a1d[gn1 * 2 + hd] = pd1; }
    }
}

// ---------------------------------------------------------------------------
// kfused: EXACT R6 version (best total 237.7): one block per bucket, 1024
// threads, LDS CSR phase 1, 8x8 phase 2 with unroll x2.
// ---------------------------------------------------------------------------
__global__ __launch_bounds__(1024) void kfused(const int* __restrict__ cursor,
                                               const int* __restrict__ binned,
                                               const uint2* __restrict__ h1h,
                                               const float* __restrict__ a1s,
                                               const float* __restrict__ a1d,
                                               const float* __restrict__ b1,
                                               const float* __restrict__ W2,
                                               const float* __restrict__ as2,
                                               const float* __restrict__ ad2,
                                               float4* __restrict__ pk,
                                               int* __restrict__ srcs,
                                               int* __restrict__ od, int N) {
    __shared__ int lsrc[CAP];                 // 32 KB
    __shared__ int ldeg[NPB], lcur[NPB], loff[NPB];
    __shared__ int swt[4];
    int b = blockIdx.x, t = threadIdx.x;
    int node0 = b * NPB;
    int nn = min(NPB, N - node0);
    int cnt = cursor[b];
    if (cnt > CAP) cnt = CAP;
    const int* bb = binned + ((long long)b << CAPSH);
    if (t < NPB) ldeg[t] = 0;
    __syncthreads();
    int pv[8];
#pragma unroll
    for (int j = 0; j < 8; j++) {
        int i = t + 1024 * j;
        pv[j] = (i < cnt) ? bb[i] : -1;
        if (pv[j] >= 0) atomicAdd(&ldeg[pv[j] >> SBITS], 1);
    }
    __syncthreads();
    // exclusive scan over nn (<=200) nodes: first 4 waves + shuffles
    {
        int v = 0, xsc = 0;
        if (t < 256) {
            v = (t < nn) ? ldeg[t] : 0;
            xsc = v;
#pragma unroll
            for (int o = 1; o < 64; o <<= 1) {
                int y = __shfl_up(xsc, o, 64);
                if ((t & 63) >= o) xsc += y;
            }
            if ((t & 63) == 63) swt[t >> 6] = xsc;
        }
        __syncthreads();
        if (t < 256) {
            int add = 0;
#pragma unroll
            for (int j = 0; j < 4; j++)
                if (j < (t >> 6)) add += swt[j];
            xsc += add;
            if (t < nn) {
                int rel = xsc - v;
                loff[t] = rel;
                lcur[t] = rel;
                od[node0 + t] = rel | (v << 14);
            }
        }
        __syncthreads();
    }
#pragma unroll
    for (int j = 0; j < 8; j++) {
        if (pv[j] >= 0) {
            int pos = atomicAdd(&lcur[pv[j] >> SBITS], 1);
            lsrc[pos] = pv[j] & SMASK;
        }
    }
    __syncthreads();
    // srcs for kagg2 (coalesced stream write)
    for (int i = t; i < cnt; i += 1024) srcs[((long long)b << CAPSH) + i] = lsrc[i];

    // ---- phase 2 (8 edges x 8 ch-quads, unroll x2) ----
    int wv = t >> 6, lane = t & 63;
    int e8 = lane >> 3, c4 = lane & 7, hd = c4 >> 2;
    bool wlane = (c4 & 3) == 0;
    for (int ni = wv; ni < nn; ni += 16) {
        int n = node0 + ni;
        float a1dn = a1d[2 * n + hd];
        int base = loff[ni], g = ldeg[ni];
        float4 acc = make_float4(0.f, 0.f, 0.f, 0.f);
        float wsum = 0.f;
        // tt = -1 is the self-loop (edge slot 0); pair (tt, tt+8) per iter
        for (int tt = e8 - 1; tt < g; tt += 16) {
            int t2 = tt + 8;
            bool p2 = t2 < g;
            int s0 = (tt < 0) ? n : lsrc[base + tt];
            int s1 = p2 ? lsrc[base + t2] : s0;       // safe addr when !p2
            // issue all four global loads back-to-back (MLP)
            float as0 = a1s[2 * s0 + hd];
            float as1 = a1s[2 * s1 + hd];
            uint2 hb0 = h1h[(size_t)s0 * 8 + c4];
            uint2 hb1 = h1h[(size_t)s1 * 8 + c4];
            float al0 = as0 + a1dn;
            al0 = al0 > 0.f ? al0 : LEAK * al0;
            float w0 = __expf(al0);
            float al1 = as1 + a1dn;
            al1 = al1 > 0.f ? al1 : LEAK * al1;
            float w1 = p2 ? __expf(al1) : 0.f;
            float2 f01 = uph(hb0.x), f23 = uph(hb0.y);
            float2 g01 = uph(hb1.x), g23 = uph(hb1.y);
            acc.x = fmaf(w0, f01.x, acc.x);
            acc.y = fmaf(w0, f01.y, acc.y);
            acc.z = fmaf(w0, f23.x, acc.z);
            acc.w = fmaf(w0, f23.y, acc.w);
            acc.x = fmaf(w1, g01.x, acc.x);
            acc.y = fmaf(w1, g01.y, acc.y);
            acc.z = fmaf(w1, g23.x, acc.z);
            acc.w = fmaf(w1, g23.y, acc.w);
            if (wlane) wsum += w0 + w1;
        }
#pragma unroll
        for (int m = 8; m < 64; m <<= 1) {
            acc.x += __shfl_xor(acc.x, m, 64);
            acc.y += __shfl_xor(acc.y, m, 64);
            acc.z += __shfl_xor(acc.z, m, 64);
            acc.w += __shfl_xor(acc.w, m, 64);
            wsum += __shfl_xor(wsum, m, 64);
        }
        float wsH = __shfl(wsum, hd * 4, 64);
        float inv = 1.f / (wsH + 1e-16f);
        float4 bv = ((const float4*)b1)[c4];
        float4 t1;
        t1.x = acc.x * inv + bv.x;
        t1.y = acc.y * inv + bv.y;
        t1.z = acc.z * inv + bv.z;
        t1.w = acc.w * inv + bv.w;
        t1.x = t1.x > 0.f ? t1.x : __expf(t1.x) - 1.f;
        t1.y = t1.y > 0.f ? t1.y : __expf(t1.y) - 1.f;
        t1.z = t1.z > 0.f ? t1.z : __expf(t1.z) - 1.f;
        t1.w = t1.w > 0.f ? t1.w : __expf(t1.w) - 1.f;
        const float4* W24 = (const float4*)W2;
        float4 wA = W24[c4 * 2], wB = W24[c4 * 2 + 1];
        float p0 = t1.x * wA.x + t1.y * wA.z + t1.z * wB.x + t1.w * wB.z;
        float p1 = t1.x * wA.y + t1.y * wA.w + t1.z * wB.y + t1.w * wB.w;
#pragma unroll
        for (int m = 1; m < 8; m <<= 1) {
            p0 += __shfl_xor(p0, m, 64);
            p1 += __shfl_xor(p1, m, 64);
        }
        if (lane == 0)
            pk[n] = make_float4(p0 * as2[0] + p1 * as2[1], p0, p1,
                                p0 * ad2[0] + p1 * ad2[1]);
    }
}

// ---------------------------------------------------------------------------
// kagg2: layer-2 gather, 32-lane subgroup per node (full lane utilization at
// deg~33), 1 packed 16B pk load per edge, log_softmax -> out.
// ---------------------------------------------------------------------------
__global__ __launch_bounds__(256) void kagg2(const int* __restrict__ od,
                                             const int* __restrict__ srcs,
                                             const float4* __restrict__ pk,
                                             const float* __restrict__ b2,
                                             float* __restrict__ out, int N) {
    int sub = threadIdx.x >> 5, k = threadIdx.x & 31;
    int n = blockIdx.x * 8 + sub;
    if (n >= N) return;
    float4 pn = pk[n];
    float adn = pn.w;
    int o = od[n];
    int base = ((n / NPB) << CAPSH) + (o & 16383);
    int g = o >> 14;
    float a0 = 0.f, a1v = 0.f, wsm = 0.f;
    // e = -1 is the self-loop
    for (int e = k - 1; e < g; e += 32) {
        float4 p = (e < 0) ? pn : pk[srcs[base + e]];
        float al = p.x + adn;
        al = al > 0.f ? al : LEAK * al;
        float w = __expf(al);
        a0 = fmaf(w, p.y, a0);
        a1v = fmaf(w, p.z, a1v);
        wsm += w;
    }
#pragma unroll
    for (int m = 1; m < 32; m <<= 1) {
        a0 += __shfl_xor(a0, m, 32);
        a1v += __shfl_xor(a1v, m, 32);
        wsm += __shfl_xor(wsm, m, 32);
    }
    if (k == 0) {
        float inv = 1.f / (wsm + 1e-16f);
        float o0 = a0 * inv + b2[0];
        float o1 = a1v * inv + b2[1];
        float mx = fmaxf(o0, o1);
        float lse = mx + __logf(__expf(o0 - mx) + __expf(o1 - mx));
        ((float2*)out)[n] = make_float2(o0 - lse, o1 - lse);
    }
}

extern "C" void kernel_launch(void* const* d_in, const int* in_sizes, int n_in,
                              void* d_out, int out_size, void* d_ws, size_t ws_size,
                              hipStream_t stream) {
    const float* x   = (const float*)d_in[0];
    const int*   ei  = (const int*)d_in[1];
    const float* W1  = (const float*)d_in[2];
    const float* as1 = (const float*)d_in[3];
    const float* ad1 = (const float*)d_in[4];
    const float* b1  = (const float*)d_in[5];
    const float* W2  = (const float*)d_in[6];
    const float* as2 = (const float*)d_in[7];
    const float* ad2 = (const float*)d_in[8];
    const float* b2  = (const float*)d_in[9];
    float* out = (float*)d_out;

    int N = out_size / 2;          // 100000
    int E = in_sizes[1] / 2;       // 3200000
    int K = (N + NPB - 1) / NPB;   // 500

    // workspace layout (4B units; pk first for 16B alignment)
    float* wsp   = (float*)d_ws;
    float4* pk   = (float4*)wsp;                     // N float4
    uint2* h1h   = (uint2*)(pk + (size_t)N);         // N*8 uint2 (fp16 h1)
    float* a1s   = (float*)(h1h + (size_t)N * 8);    // N*2
    float* a1d   = a1s + (size_t)N * 2;              // N*2
    int* od      = (int*)(a1d + (size_t)N * 2);      // N
    int* srcs    = od + N;                           // K*CAP
    int* binned  = srcs + (size_t)K * CAP;           // K*CAP
    int* cursor  = binned + (size_t)K * CAP;         // K

    int nblkB = (E + CHUNKB - 1) / CHUNKB;           // 391

    // k1 first: its block 0 zeroes cursor (replaces hipMemsetAsync dispatch)
    k1<<<(N + 63) / 64, 256, 0, stream>>>(x, W1, as1, ad1, h1h, a1s, a1d, N,
                                          cursor, K);
    kbin<<<nblkB, 512, 0, stream>>>(ei, E, K, cursor, binned);
    kfused<<<K, 1024, 0, stream>>>(cursor, binned, h1h, a1s, a1d,
                                   b1, W2, as2, ad2, pk, srcs, od, N);
    kagg2<<<(N + 7) / 8, 256, 0, stream>>>(od, srcs, pk, b2, out, N);
}

// Round 9
// 224.528 us; speedup vs baseline: 1.0745x; 1.0284x over previous
//
#include <hip/hip_runtime.h>
#include <hip/hip_bf16.h>
#include <hip/hip_fp16.h>

#define LEAK   0.2f
#define NPB    200      // nodes per dst-bucket -> K = ceil(N/NPB) = 500
#define CAP    8192     // padded per-bucket capacity (mean 6400, sigma 80)
#define CAPSH  13       // log2(CAP)
#define SBITS  17       // bits for src id (N=100000 < 2^17)
#define SMASK  0x1FFFF
#define CHUNKB 8192     // edges per bin-role block (16 per thread at 512 thr)

__device__ __forceinline__ unsigned pkh(float a, float b) {
    __half2 h = __floats2half2_rn(a, b);
    return *(unsigned*)&h;
}
__device__ __forceinline__ float2 uph(unsigned u) {
    __half2 h = *(__half2*)&u;
    return __half22float2(h);
}

// ---------------------------------------------------------------------------
// kpre: fat kernel fusing the two data-independent stages.
//   blocks [0, NBIN):   bin role  == R8's proven write-coalesced kbin
//   blocks [NBIN, ...): k1 role   == x@W1 (adapted to 512 thr: 1 node/thread)
// Why safe now (vs R1's failed fat kernel): bin role ALREADY uses 56 KB LDS
// at 512 thr / 2 blocks/CU in its best-measured form, so the shared-LDS
// coupling costs it nothing; k1 role rises 12 -> 16 waves/CU. Roles use
// complementary pipes (bin: memory/atomics, k1: FMA/LDS) -> overlap.
// LDS: one 57,380 B carved arena -> 2 blocks/CU both roles.
// ---------------------------------------------------------------------------
__global__ __launch_bounds__(512) void kpre(const int* __restrict__ ei, int E, int K,
                                            int NBIN,
                                            int* __restrict__ cursor,
                                            int* __restrict__ binned,
                                            const float* __restrict__ x,
                                            const float* __restrict__ W1,
                                            const float* __restrict__ atts,
                                            const float* __restrict__ attd,
                                            uint2* __restrict__ h1h,
                                            float* __restrict__ a1s,
                                            float* __restrict__ a1d, int N) {
    __shared__ __align__(16) char smem[57380];
    int t = threadIdx.x;

    if (blockIdx.x < NBIN) {
        // ================= bin role (R8 kbin, verbatim logic) =================
        int* hist = (int*)smem;                 // 512
        int* gb    = hist + 512;                // 512
        int* lbase = gb + 512;                  // 512
        int* lcur  = lbase + 512;               // 512           (ends 8192 B)
        unsigned short* rbk = (unsigned short*)(lcur + 512);   // 8192 (16 KB)
        int* sv    = (int*)(rbk + CHUNKB);      // 8192 (32 KB)  (ends 57344 B)
        int* swt   = sv + CHUNKB;               // 8
        int* probe = swt + 8;                   // 1
        hist[t] = 0;
        if (t == 0) *probe = 0;
        __syncthreads();
        // int64 LE => odd int32 slots of first 1024 values are 0
        if (t < 256) {
            int zc = 0;
#pragma unroll
            for (int j = 0; j < 4; j++) zc += (ei[(t * 4 + j) * 2 + 1] == 0) ? 1 : 0;
            if (zc) atomicAdd(probe, zc);
        }
        __syncthreads();
        int f = (*probe == 1024);
        int e0 = blockIdx.x * CHUNKB;
        int ss[16], dd[16];
#pragma unroll
        for (int i = 0; i < 16; i++) {
            int e = e0 + t + 512 * i;
            ss[i] = -1;
            dd[i] = 0;
            if (e < E) {
                int s, d;
                if (f) { s = ei[2 * e]; d = ei[2 * (e + E)]; }
                else   { s = ei[e];     d = ei[e + E]; }
                ss[i] = s;
                dd[i] = d;
                atomicAdd(&hist[d / NPB], 1);
            }
        }
        __syncthreads();
        // global reservation + LDS exclusive scan over 512 bucket slots
        int h = (t < K) ? hist[t] : 0;
        if (h) gb[t] = (t << CAPSH) + atomicAdd(&cursor[t], h);
        int xsc = h;
#pragma unroll
        for (int o = 1; o < 64; o <<= 1) {
            int y = __shfl_up(xsc, o, 64);
            if ((t & 63) >= o) xsc += y;
        }
        if ((t & 63) == 63) swt[t >> 6] = xsc;
        __syncthreads();
        int add = 0;
#pragma unroll
        for (int j = 0; j < 8; j++)
            if (j < (t >> 6)) add += swt[j];
        int lb = xsc - h + add;          // exclusive prefix = LDS run base
        lbase[t] = lb;
        lcur[t] = lb;
        __syncthreads();
        // fill slot->bucket map + scatter edges into LDS
        for (int j = 0; j < h; j++) rbk[lb + j] = (unsigned short)t;
#pragma unroll
        for (int i = 0; i < 16; i++) {
            if (ss[i] >= 0) {
                int bk = dd[i] / NPB;
                int dloc = dd[i] - bk * NPB;
                int pos = atomicAdd(&lcur[bk], 1);
                sv[pos] = ss[i] | (dloc << SBITS);
            }
        }
        __syncthreads();
        // coalesced copy-out: consecutive slots -> consecutive global addrs
        int tot = min(CHUNKB, E - e0);
        for (int i = t; i < tot; i += 512) {
            int bk = rbk[i];
            int gpos = gb[bk] + (i - lbase[bk]);
            if (gpos < ((bk + 1) << CAPSH))           // OOB safety clamp
                binned[gpos] = sv[i];
        }
    } else {
        // ================= k1 role (512 thr, 1 node/thread) =================
        int b = blockIdx.x - NBIN;
        float* Ws = (float*)smem;                // 16 KB
        float* xs = Ws + 4096;                   // 33 KB (64 x 132)
        const float4* W4 = (const float4*)W1;
        float4* Ws4 = (float4*)Ws;
#pragma unroll
        for (int i = 0; i < 2; i++) Ws4[t + 512 * i] = W4[t + 512 * i];
        long long node0 = (long long)b * 64;
        const float4* x4 = (const float4*)x;
        float4* xs4 = (float4*)xs;
#pragma unroll
        for (int i = 0; i < 4; i++) {
            int idx = t + 512 * i;
            int row = idx >> 5, col = idx & 31;
            long long n = node0 + row;
            float4 v = make_float4(0.f, 0.f, 0.f, 0.f);
            if (n < N) v = x4[n * 32 + col];
            xs4[row * 33 + col] = v;
        }
        __syncthreads();

        int cg = t & 7, ns = t >> 3;             // ns in 0..63: one node
        const float4* xr = (const float4*)(xs + ns * 132);
        float acc[4] = {0.f, 0.f, 0.f, 0.f};
#pragma unroll 8
        for (int k4 = 0; k4 < 32; k4++) {
            float4 xa = xr[k4];
            float av[4] = {xa.x, xa.y, xa.z, xa.w};
#pragma unroll
            for (int i = 0; i < 4; i++) {
                float4 w = Ws4[(k4 * 4 + i) * 8 + cg];
                acc[0] = fmaf(av[i], w.x, acc[0]);
                acc[1] = fmaf(av[i], w.y, acc[1]);
                acc[2] = fmaf(av[i], w.z, acc[2]);
                acc[3] = fmaf(av[i], w.w, acc[3]);
            }
        }
        long long gn = node0 + ns;
        if (gn < N) h1h[gn * 8 + cg] = make_uint2(pkh(acc[0], acc[1]),
                                                  pkh(acc[2], acc[3]));
        float ps = 0.f, pd = 0.f;
#pragma unroll
        for (int i = 0; i < 4; i++) {
            ps = fmaf(acc[i], atts[cg * 4 + i], ps);
            pd = fmaf(acc[i], attd[cg * 4 + i], pd);
        }
#pragma unroll
        for (int m = 1; m < 4; m <<= 1) {
            ps += __shfl_xor(ps, m, 64);
            pd += __shfl_xor(pd, m, 64);
        }
        if ((cg & 3) == 0) {
            int hd = cg >> 2;
            if (gn < N) { a1s[gn * 2 + hd] = ps; a1d[gn * 2 + hd] = pd; }
        }
    }
}

// ---------------------------------------------------------------------------
// kfused: EXACT R8 version (proven): one block per bucket, 1024 threads,
// LDS CSR phase 1, 8x8 phase 2 with unroll x2.
// ---------------------------------------------------------------------------
__global__ __launch_bounds__(1024) void kfused(const int* __restrict__ cursor,
                                               const int* __restrict__ binned,
                                               const uint2* __restrict__ h1h,
                                               const float* __restrict__ a1s,
                                               const float* __restrict__ a1d,
                                               const float* __restrict__ b1,
                                               const float* __restrict__ W2,
                                               const float* __restrict__ as2,
                                               const float* __restrict__ ad2,
                                               float4* __restrict__ pk,
                                               int* __restrict__ srcs,
                                               int* __restrict__ od, int N) {
    __shared__ int lsrc[CAP];                 // 32 KB
    __shared__ int ldeg[NPB], lcur[NPB], loff[NPB];
    __shared__ int swt[4];
    int b = blockIdx.x, t = threadIdx.x;
    int node0 = b * NPB;
    int nn = min(NPB, N - node0);
    int cnt = cursor[b];
    if (cnt > CAP) cnt = CAP;
    const int* bb = binned + ((long long)b << CAPSH);
    if (t < NPB) ldeg[t] = 0;
    __syncthreads();
    int pv[8];
#pragma unroll
    for (int j = 0; j < 8; j++) {
        int i = t + 1024 * j;
        pv[j] = (i < cnt) ? bb[i] : -1;
        if (pv[j] >= 0) atomicAdd(&ldeg[pv[j] >> SBITS], 1);
    }
    __syncthreads();
    // exclusive scan over nn (<=200) nodes: first 4 waves + shuffles
    {
        int v = 0, xsc = 0;
        if (t < 256) {
            v = (t < nn) ? ldeg[t] : 0;
            xsc = v;
#pragma unroll
            for (int o = 1; o < 64; o <<= 1) {
                int y = __shfl_up(xsc, o, 64);
                if ((t & 63) >= o) xsc += y;
            }
            if ((t & 63) == 63) swt[t >> 6] = xsc;
        }
        __syncthreads();
        if (t < 256) {
            int add = 0;
#pragma unroll
            for (int j = 0; j < 4; j++)
                if (j < (t >> 6)) add += swt[j];
            xsc += add;
            if (t < nn) {
                int rel = xsc - v;
                loff[t] = rel;
                lcur[t] = rel;
                od[node0 + t] = rel | (v << 14);
            }
        }
        __syncthreads();
    }
#pragma unroll
    for (int j = 0; j < 8; j++) {
        if (pv[j] >= 0) {
            int pos = atomicAdd(&lcur[pv[j] >> SBITS], 1);
            lsrc[pos] = pv[j] & SMASK;
        }
    }
    __syncthreads();
    // srcs for kagg2 (coalesced stream write)
    for (int i = t; i < cnt; i += 1024) srcs[((long long)b << CAPSH) + i] = lsrc[i];

    // ---- phase 2 (8 edges x 8 ch-quads, unroll x2) ----
    int wv = t >> 6, lane = t & 63;
    int e8 = lane >> 3, c4 = lane & 7, hd = c4 >> 2;
    bool wlane = (c4 & 3) == 0;
    for (int ni = wv; ni < nn; ni += 16) {
        int n = node0 + ni;
        float a1dn = a1d[2 * n + hd];
        int base = loff[ni], g = ldeg[ni];
        float4 acc = make_float4(0.f, 0.f, 0.f, 0.f);
        float wsum = 0.f;
        // tt = -1 is the self-loop (edge slot 0); pair (tt, tt+8) per iter
        for (int tt = e8 - 1; tt < g; tt += 16) {
            int t2 = tt + 8;
            bool p2 = t2 < g;
            int s0 = (tt < 0) ? n : lsrc[base + tt];
            int s1 = p2 ? lsrc[base + t2] : s0;       // safe addr when !p2
            // issue all four global loads back-to-back (MLP)
            float as0 = a1s[2 * s0 + hd];
            float as1 = a1s[2 * s1 + hd];
            uint2 hb0 = h1h[(size_t)s0 * 8 + c4];
            uint2 hb1 = h1h[(size_t)s1 * 8 + c4];
            float al0 = as0 + a1dn;
            al0 = al0 > 0.f ? al0 : LEAK * al0;
            float w0 = __expf(al0);
            float al1 = as1 + a1dn;
            al1 = al1 > 0.f ? al1 : LEAK * al1;
            float w1 = p2 ? __expf(al1) : 0.f;
            float2 f01 = uph(hb0.x), f23 = uph(hb0.y);
            float2 g01 = uph(hb1.x), g23 = uph(hb1.y);
            acc.x = fmaf(w0, f01.x, acc.x);
            acc.y = fmaf(w0, f01.y, acc.y);
            acc.z = fmaf(w0, f23.x, acc.z);
            acc.w = fmaf(w0, f23.y, acc.w);
            acc.x = fmaf(w1, g01.x, acc.x);
            acc.y = fmaf(w1, g01.y, acc.y);
            acc.z = fmaf(w1, g23.x, acc.z);
            acc.w = fmaf(w1, g23.y, acc.w);
            if (wlane) wsum += w0 + w1;
        }
#pragma unroll
        for (int m = 8; m < 64; m <<= 1) {
            acc.x += __shfl_xor(acc.x, m, 64);
            acc.y += __shfl_xor(acc.y, m, 64);
            acc.z += __shfl_xor(acc.z, m, 64);
            acc.w += __shfl_xor(acc.w, m, 64);
            wsum += __shfl_xor(wsum, m, 64);
        }
        float wsH = __shfl(wsum, hd * 4, 64);
        float inv = 1.f / (wsH + 1e-16f);
        float4 bv = ((const float4*)b1)[c4];
        float4 t1;
        t1.x = acc.x * inv + bv.x;
        t1.y = acc.y * inv + bv.y;
        t1.z = acc.z * inv + bv.z;
        t1.w = acc.w * inv + bv.w;
        t1.x = t1.x > 0.f ? t1.x : __expf(t1.x) - 1.f;
        t1.y = t1.y > 0.f ? t1.y : __expf(t1.y) - 1.f;
        t1.z = t1.z > 0.f ? t1.z : __expf(t1.z) - 1.f;
        t1.w = t1.w > 0.f ? t1.w : __expf(t1.w) - 1.f;
        const float4* W24 = (const float4*)W2;
        float4 wA = W24[c4 * 2], wB = W24[c4 * 2 + 1];
        float p0 = t1.x * wA.x + t1.y * wA.z + t1.z * wB.x + t1.w * wB.z;
        float p1 = t1.x * wA.y + t1.y * wA.w + t1.z * wB.y + t1.w * wB.w;
#pragma unroll
        for (int m = 1; m < 8; m <<= 1) {
            p0 += __shfl_xor(p0, m, 64);
            p1 += __shfl_xor(p1, m, 64);
        }
        if (lane == 0)
            pk[n] = make_float4(p0 * as2[0] + p1 * as2[1], p0, p1,
                                p0 * ad2[0] + p1 * ad2[1]);
    }
}

// ---------------------------------------------------------------------------
// kagg2: layer-2 gather, 32-lane subgroup per node (full lane utilization at
// deg~33), 1 packed 16B pk load per edge, log_softmax -> out.
// ---------------------------------------------------------------------------
__global__ __launch_bounds__(256) void kagg2(const int* __restrict__ od,
                                             const int* __restrict__ srcs,
                                             const float4* __restrict__ pk,
                                             const float* __restrict__ b2,
                                             float* __restrict__ out, int N) {
    int sub = threadIdx.x >> 5, k = threadIdx.x & 31;
    int n = blockIdx.x * 8 + sub;
    if (n >= N) return;
    float4 pn = pk[n];
    float adn = pn.w;
    int o = od[n];
    int base = ((n / NPB) << CAPSH) + (o & 16383);
    int g = o >> 14;
    float a0 = 0.f, a1v = 0.f, wsm = 0.f;
    // e = -1 is the self-loop
    for (int e = k - 1; e < g; e += 32) {
        float4 p = (e < 0) ? pn : pk[srcs[base + e]];
        float al = p.x + adn;
        al = al > 0.f ? al : LEAK * al;
        float w = __expf(al);
        a0 = fmaf(w, p.y, a0);
        a1v = fmaf(w, p.z, a1v);
        wsm += w;
    }
#pragma unroll
    for (int m = 1; m < 32; m <<= 1) {
        a0 += __shfl_xor(a0, m, 32);
        a1v += __shfl_xor(a1v, m, 32);
        wsm += __shfl_xor(wsm, m, 32);
    }
    if (k == 0) {
        float inv = 1.f / (wsm + 1e-16f);
        float o0 = a0 * inv + b2[0];
        float o1 = a1v * inv + b2[1];
        float mx = fmaxf(o0, o1);
        float lse = mx + __logf(__expf(o0 - mx) + __expf(o1 - mx));
        ((float2*)out)[n] = make_float2(o0 - lse, o1 - lse);
    }
}

extern "C" void kernel_launch(void* const* d_in, const int* in_sizes, int n_in,
                              void* d_out, int out_size, void* d_ws, size_t ws_size,
                              hipStream_t stream) {
    const float* x   = (const float*)d_in[0];
    const int*   ei  = (const int*)d_in[1];
    const float* W1  = (const float*)d_in[2];
    const float* as1 = (const float*)d_in[3];
    const float* ad1 = (const float*)d_in[4];
    const float* b1  = (const float*)d_in[5];
    const float* W2  = (const float*)d_in[6];
    const float* as2 = (const float*)d_in[7];
    const float* ad2 = (const float*)d_in[8];
    const float* b2  = (const float*)d_in[9];
    float* out = (float*)d_out;

    int N = out_size / 2;          // 100000
    int E = in_sizes[1] / 2;       // 3200000
    int K = (N + NPB - 1) / NPB;   // 500

    // workspace layout (4B units; pk first for 16B alignment)
    float* wsp   = (float*)d_ws;
    float4* pk   = (float4*)wsp;                     // N float4
    uint2* h1h   = (uint2*)(pk + (size_t)N);         // N*8 uint2 (fp16 h1)
    float* a1s   = (float*)(h1h + (size_t)N * 8);    // N*2
    float* a1d   = a1s + (size_t)N * 2;              // N*2
    int* od      = (int*)(a1d + (size_t)N * 2);      // N
    int* srcs    = od + N;                           // K*CAP
    int* binned  = srcs + (size_t)K * CAP;           // K*CAP
    int* cursor  = binned + (size_t)K * CAP;         // K

    int NBIN = (E + CHUNKB - 1) / CHUNKB;            // 391
    int NK1  = (N + 63) / 64;                        // 1563

    hipMemsetAsync(cursor, 0, K * sizeof(int), stream);
    kpre<<<NBIN + NK1, 512, 0, stream>>>(ei, E, K, NBIN, cursor, binned,
                                         x, W1, as1, ad1, h1h, a1s, a1d, N);
    kfused<<<K, 1024, 0, stream>>>(cursor, binned, h1h, a1s, a1d,
                                   b1, W2, as2, ad2, pk, srcs, od, N);
    kagg2<<<(N + 7) / 8, 256, 0, stream>>>(od, srcs, pk, b2, out, N);
}